// Round 1
// baseline (809.591 us; speedup 1.0000x reference)
//
#include <hip/hip_runtime.h>

typedef __bf16 bf16;
typedef __bf16 bf16x8 __attribute__((ext_vector_type(8)));
typedef float  f32x4  __attribute__((ext_vector_type(4)));

#define B_  8
#define N_  2048
#define D_  512
#define H_  8
#define DH_ 64
static constexpr float SC2 = 0.18033688011112042f; // (1/8) * log2(e)

#if defined(__has_builtin)
#if __has_builtin(__builtin_amdgcn_exp2f)
#define EXP2(x) __builtin_amdgcn_exp2f(x)
#else
#define EXP2(x) exp2f(x)
#endif
#else
#define EXP2(x) exp2f(x)
#endif

__device__ __forceinline__ f32x4 mfma16(bf16x8 a, bf16x8 b, f32x4 c) {
  return __builtin_amdgcn_mfma_f32_16x16x32_bf16(a, b, c, 0, 0, 0);
}

__device__ __forceinline__ void gload_lds16(const void* g, void* l) {
  __builtin_amdgcn_global_load_lds((__attribute__((address_space(1))) void*)g,
                                   (__attribute__((address_space(3))) void*)l, 16, 0, 0);
}

// ---- convert x (f32) -> bf16, 8 elems/thread, exact cover 8.39M ----
__global__ void k_cvt_x(const float* __restrict__ x, bf16* __restrict__ xb) {
  int i = blockIdx.x * blockDim.x + threadIdx.x;
  const float4* p = (const float4*)x;
  float4 a = p[2*i], b = p[2*i+1];
  bf16x8 o;
  o[0]=(bf16)a.x; o[1]=(bf16)a.y; o[2]=(bf16)a.z; o[3]=(bf16)a.w;
  o[4]=(bf16)b.x; o[5]=(bf16)b.y; o[6]=(bf16)b.z; o[7]=(bf16)b.w;
  ((bf16x8*)xb)[i] = o;
}

// ---- transpose-convert one 512x512 f32 weight -> bf16 W^T ----
__global__ void k_wt(const float* __restrict__ w, bf16* __restrict__ wt) {
  __shared__ float t[64][65];
  const int c0 = blockIdx.x * 64, k0 = blockIdx.y * 64;
  const int r = threadIdx.x >> 2, q4 = (threadIdx.x & 3) * 16;
#pragma unroll
  for (int j = 0; j < 16; j += 4) {
    float4 v = *(const float4*)(w + (k0 + r) * 512 + c0 + q4 + j);
    t[r][q4+j] = v.x; t[r][q4+j+1] = v.y; t[r][q4+j+2] = v.z; t[r][q4+j+3] = v.w;
  }
  __syncthreads();
  const int c = threadIdx.x >> 2, kq = (threadIdx.x & 3) * 16;
  bf16x8 o0, o1;
#pragma unroll
  for (int j = 0; j < 8; ++j) { o0[j] = (bf16)t[kq+j][c]; o1[j] = (bf16)t[kq+8+j][c]; }
  *(bf16x8*)(wt + (c0 + c) * 512 + k0 + kq) = o0;
  *(bf16x8*)(wt + (c0 + c) * 512 + k0 + kq + 8) = o1;
}

// ---- 128x128 tile GEMM, K=512, A[M][512] bf16, Bt[Ncols][512] bf16 ----
// MODE 0: C -> scatter into Q [bh][n][64], K [bh][n][64], V^T [bh][64][n] (cols: 0-511 q, 512-1023 k, 1024-1535 v)
// MODE 1: C -> f32 out[M][512] + bias
template<int MODE>
__global__ void k_gemm(const bf16* __restrict__ A, const bf16* __restrict__ Bt,
                       bf16* __restrict__ qo, bf16* __restrict__ ko, bf16* __restrict__ vo,
                       float* __restrict__ outp, const float* __restrict__ bo) {
  __shared__ bf16 lA[128 * 64];
  __shared__ bf16 lB[128 * 64];
  const int tid = threadIdx.x;
  const int wid = tid >> 6, lane = tid & 63;
  const int l15 = lane & 15, lq = lane >> 4;
  const int wr = wid >> 1, wc = wid & 1;
  const long long rowtile = (long long)blockIdx.x * 128;
  const long long coltile = (long long)blockIdx.y * 128;

  const bf16* gA[4]; const bf16* gB[4];
  bf16* lAc[4]; bf16* lBc[4];
#pragma unroll
  for (int i = 0; i < 4; ++i) {
    int ci = wid * 4 + i;
    int row = ci * 8 + (lane >> 3);
    int c8 = (lane & 7) ^ (row & 7);          // pre-swizzled global source
    gA[i] = A + (rowtile + row) * 512 + c8 * 8;
    gB[i] = Bt + (coltile + row) * 512 + c8 * 8;
    lAc[i] = &lA[ci * 512];
    lBc[i] = &lB[ci * 512];
  }
  unsigned aoff[4][2], boff[4][2];
#pragma unroll
  for (int mi = 0; mi < 4; ++mi) {
#pragma unroll
    for (int ks = 0; ks < 2; ++ks) {
      int R = l15 + 16 * mi + 64 * wr;
      aoff[mi][ks] = R * 128 + ((((ks << 2) | lq) ^ (R & 7)) << 4);
      int Rb = l15 + 16 * mi + 64 * wc;
      boff[mi][ks] = Rb * 128 + ((((ks << 2) | lq) ^ (Rb & 7)) << 4);
    }
  }
  f32x4 acc[4][4] = {};
  for (int kt = 0; kt < 8; ++kt) {
#pragma unroll
    for (int i = 0; i < 4; ++i) gload_lds16(gA[i], lAc[i]);
#pragma unroll
    for (int i = 0; i < 4; ++i) gload_lds16(gB[i], lBc[i]);
#pragma unroll
    for (int i = 0; i < 4; ++i) { gA[i] += 64; gB[i] += 64; }
    __syncthreads();
#pragma unroll
    for (int ks = 0; ks < 2; ++ks) {
      bf16x8 af[4], bfr[4];
#pragma unroll
      for (int mi = 0; mi < 4; ++mi) af[mi] = *(const bf16x8*)((const char*)lA + aoff[mi][ks]);
#pragma unroll
      for (int nf = 0; nf < 4; ++nf) bfr[nf] = *(const bf16x8*)((const char*)lB + boff[nf][ks]);
#pragma unroll
      for (int mi = 0; mi < 4; ++mi)
#pragma unroll
        for (int nf = 0; nf < 4; ++nf)
          acc[mi][nf] = mfma16(af[mi], bfr[nf], acc[mi][nf]);
    }
    __syncthreads();
  }
  if (MODE == 0) {
#pragma unroll
    for (int nf = 0; nf < 4; ++nf) {
      const int col = (int)coltile + 64 * wc + nf * 16 + l15;
      const int mat = col >> 9, c5 = col & 511, hh = c5 >> 6, dh = c5 & 63;
#pragma unroll
      for (int mi = 0; mi < 4; ++mi) {
#pragma unroll
        for (int r = 0; r < 4; ++r) {
          const int R = (int)rowtile + 64 * wr + mi * 16 + lq * 4 + r;
          const int bb = R >> 11, n = R & 2047;
          const bf16 bv = (bf16)acc[mi][nf][r];
          const long long bh = bb * 8 + hh;
          if (mat == 0)      qo[(bh * 2048 + n) * 64 + dh] = bv;
          else if (mat == 1) ko[(bh * 2048 + n) * 64 + dh] = bv;
          else               vo[(bh * 64 + dh) * 2048 + n] = bv;
        }
      }
    }
  } else {
#pragma unroll
    for (int nf = 0; nf < 4; ++nf) {
      const int col = (int)coltile + 64 * wc + nf * 16 + l15;
      const float bias = bo[col];
#pragma unroll
      for (int mi = 0; mi < 4; ++mi)
#pragma unroll
        for (int r = 0; r < 4; ++r) {
          const long long R = rowtile + 64 * wr + mi * 16 + lq * 4 + r;
          outp[R * 512 + col] = acc[mi][nf][r] + bias;
        }
    }
  }
}

// ---- flash attention: block = (b, qtile of 64 rows), 8 waves = 8 heads ----
__global__ __launch_bounds__(512, 2) void k_attn(
    const bf16* __restrict__ qb, const bf16* __restrict__ kb, const bf16* __restrict__ vt,
    const float* __restrict__ mask, bf16* __restrict__ ao) {
  __shared__ bf16 plds[8 * 64 * 64];   // per-wave 8KB P buffer (no barriers)
  const int tid = threadIdx.x;
  const int wid = tid >> 6, lane = tid & 63;
  const int l15 = lane & 15, lq = lane >> 4;
  const int b = blockIdx.y, qt = blockIdx.x, h = wid;
  const int qbase = qt * 64;
  const bf16* Q = qb + (long long)(b * H_ + h) * N_ * DH_;
  const bf16* K = kb + (long long)(b * H_ + h) * N_ * DH_;
  const bf16* V = vt + (long long)(b * H_ + h) * DH_ * N_;
  const float* mrow = mask + ((long long)b * N_ + qbase) * N_;
  char* pbase = (char*)plds + wid * 8192;

  bf16x8 qf[4][2];
#pragma unroll
  for (int mi = 0; mi < 4; ++mi)
#pragma unroll
    for (int ks = 0; ks < 2; ++ks)
      qf[mi][ks] = *(const bf16x8*)(Q + (qbase + l15 + 16 * mi) * 64 + ks * 32 + lq * 8);

  f32x4 o[4][4] = {};
  float lsum[4][4] = {};   // [mi][r]

  for (int jt = 0; jt < 32; ++jt) {
    const int jb = jt * 64;
    bf16x8 kf[4][2], vf[4][2];
#pragma unroll
    for (int nf = 0; nf < 4; ++nf) {
#pragma unroll
      for (int ks = 0; ks < 2; ++ks) {
        kf[nf][ks] = *(const bf16x8*)(K + (jb + l15 + 16 * nf) * 64 + ks * 32 + lq * 8);
        vf[nf][ks] = *(const bf16x8*)(V + (l15 + 16 * nf) * 2048 + jb + ks * 32 + lq * 8);
      }
    }
#pragma unroll
    for (int mi = 0; mi < 4; ++mi) {
      f32x4 s[4];
#pragma unroll
      for (int nf = 0; nf < 4; ++nf) {
        f32x4 z = {0.f, 0.f, 0.f, 0.f};
        s[nf] = mfma16(qf[mi][0], kf[nf][0], z);
      }
#pragma unroll
      for (int nf = 0; nf < 4; ++nf)
        s[nf] = mfma16(qf[mi][1], kf[nf][1], s[nf]);
      // logits = dot*SC2*(1+mask); no running max needed (bounded logits)
#pragma unroll
      for (int nf = 0; nf < 4; ++nf) {
        const int colL = nf * 16 + l15;
        const int colg = jb + colL;
#pragma unroll
        for (int r = 0; r < 4; ++r) {
          const int rowL = mi * 16 + lq * 4 + r;
          float mk = mrow[rowL * 2048 + colg];
          float dsc = s[nf][r] * SC2;
          float p = EXP2(fmaf(dsc, mk, dsc));
          lsum[mi][r] += p;
          *(bf16*)(pbase + rowL * 128 + (((colL >> 3) ^ (rowL & 7)) << 4) + (colL & 7) * 2) = (bf16)p;
        }
      }
#pragma unroll
      for (int ks2 = 0; ks2 < 2; ++ks2) {
        const int arow = l15 + 16 * mi;
        bf16x8 pa = *(const bf16x8*)(pbase + arow * 128 + ((((ks2 << 2) | lq) ^ (arow & 7)) << 4));
#pragma unroll
        for (int nf2 = 0; nf2 < 4; ++nf2)
          o[mi][nf2] = mfma16(pa, vf[nf2][ks2], o[mi][nf2]);
      }
    }
  }
  float rinv[4][4];
#pragma unroll
  for (int mi = 0; mi < 4; ++mi)
#pragma unroll
    for (int r = 0; r < 4; ++r) {
      float v = lsum[mi][r];
      v += __shfl_xor(v, 1); v += __shfl_xor(v, 2);
      v += __shfl_xor(v, 4); v += __shfl_xor(v, 8);
      rinv[mi][r] = 1.0f / v;
    }
#pragma unroll
  for (int mi = 0; mi < 4; ++mi)
#pragma unroll
    for (int nf = 0; nf < 4; ++nf)
#pragma unroll
      for (int r = 0; r < 4; ++r) {
        const long long rowg = (long long)b * N_ + qbase + mi * 16 + lq * 4 + r;
        const int col = h * 64 + nf * 16 + l15;
        ao[rowg * 512 + col] = (bf16)(o[mi][nf][r] * rinv[mi][r]);
      }
}

extern "C" void kernel_launch(void* const* d_in, const int* in_sizes, int n_in,
                              void* d_out, int out_size, void* d_ws, size_t ws_size,
                              hipStream_t stream) {
  const float* x    = (const float*)d_in[0];
  const float* mask = (const float*)d_in[1];
  const float* Wq   = (const float*)d_in[2];
  const float* Wk   = (const float*)d_in[3];
  const float* Wv   = (const float*)d_in[4];
  const float* Wo   = (const float*)d_in[5];
  const float* bo   = (const float*)d_in[6];
  float* out = (float*)d_out;
  char* ws = (char*)d_ws;

  const size_t SZ_XB = (size_t)16384 * 512 * 2;   // 16 MB  (x in bf16; reused as AO)
  const size_t SZ_W3 = (size_t)1536 * 512 * 2;    // 1.5 MB
  const size_t SZ_WO = (size_t)512 * 512 * 2;     // 0.5 MB
  const size_t SZ_T  = (size_t)64 * 2048 * 64 * 2;// 16 MB each

  bf16* xb    = (bf16*)ws;
  bf16* wqkvT = (bf16*)(ws + SZ_XB);
  bf16* woT   = (bf16*)(ws + SZ_XB + SZ_W3);
  bf16* qbuf  = (bf16*)(ws + SZ_XB + SZ_W3 + SZ_WO);
  bf16* kbuf  = (bf16*)((char*)qbuf + SZ_T);
  bf16* vtb   = (bf16*)((char*)kbuf + SZ_T);
  bf16* aob   = xb;  // x dead after QKV GEMM

  k_cvt_x<<<dim3(4096), dim3(256), 0, stream>>>(x, xb);
  k_wt<<<dim3(8, 8), dim3(256), 0, stream>>>(Wq, wqkvT);
  k_wt<<<dim3(8, 8), dim3(256), 0, stream>>>(Wk, wqkvT + 512 * 512);
  k_wt<<<dim3(8, 8), dim3(256), 0, stream>>>(Wv, wqkvT + 2 * 512 * 512);
  k_wt<<<dim3(8, 8), dim3(256), 0, stream>>>(Wo, woT);
  k_gemm<0><<<dim3(128, 12), dim3(256), 0, stream>>>(xb, wqkvT, qbuf, kbuf, vtb, nullptr, nullptr);
  k_attn<<<dim3(32, 8), dim3(512), 0, stream>>>(qbuf, kbuf, vtb, mask, aob);
  k_gemm<1><<<dim3(128, 4), dim3(256), 0, stream>>>(aob, woT, nullptr, nullptr, nullptr, out, bo);
}

// Round 2
// 633.135 us; speedup vs baseline: 1.2787x; 1.2787x over previous
//
#include <hip/hip_runtime.h>

typedef __bf16 bf16;
typedef __bf16 bf16x8 __attribute__((ext_vector_type(8)));
typedef float  f32x4  __attribute__((ext_vector_type(4)));

#define B_  8
#define N_  2048
#define D_  512
#define H_  8
#define DH_ 64
static constexpr float SC2 = 0.18033688011112042f; // (1/8) * log2(e)

#if defined(__has_builtin)
#if __has_builtin(__builtin_amdgcn_exp2f)
#define EXP2(x) __builtin_amdgcn_exp2f(x)
#else
#define EXP2(x) exp2f(x)
#endif
#else
#define EXP2(x) exp2f(x)
#endif

__device__ __forceinline__ f32x4 mfma16(bf16x8 a, bf16x8 b, f32x4 c) {
  return __builtin_amdgcn_mfma_f32_16x16x32_bf16(a, b, c, 0, 0, 0);
}

__device__ __forceinline__ void gload_lds16(const void* g, void* l) {
  __builtin_amdgcn_global_load_lds((__attribute__((address_space(1))) void*)g,
                                   (__attribute__((address_space(3))) void*)l, 16, 0, 0);
}

// ---- convert x (f32) -> bf16, 8 elems/thread, exact cover 8.39M ----
__global__ void k_cvt_x(const float* __restrict__ x, bf16* __restrict__ xb) {
  int i = blockIdx.x * blockDim.x + threadIdx.x;
  const float4* p = (const float4*)x;
  float4 a = p[2*i], b = p[2*i+1];
  bf16x8 o;
  o[0]=(bf16)a.x; o[1]=(bf16)a.y; o[2]=(bf16)a.z; o[3]=(bf16)a.w;
  o[4]=(bf16)b.x; o[5]=(bf16)b.y; o[6]=(bf16)b.z; o[7]=(bf16)b.w;
  ((bf16x8*)xb)[i] = o;
}

// ---- transpose-convert one 512x512 f32 weight -> bf16 W^T ----
__global__ void k_wt(const float* __restrict__ w, bf16* __restrict__ wt) {
  __shared__ float t[64][65];
  const int c0 = blockIdx.x * 64, k0 = blockIdx.y * 64;
  const int r = threadIdx.x >> 2, q4 = (threadIdx.x & 3) * 16;
#pragma unroll
  for (int j = 0; j < 16; j += 4) {
    float4 v = *(const float4*)(w + (k0 + r) * 512 + c0 + q4 + j);
    t[r][q4+j] = v.x; t[r][q4+j+1] = v.y; t[r][q4+j+2] = v.z; t[r][q4+j+3] = v.w;
  }
  __syncthreads();
  const int c = threadIdx.x >> 2, kq = (threadIdx.x & 3) * 16;
  bf16x8 o0, o1;
#pragma unroll
  for (int j = 0; j < 8; ++j) { o0[j] = (bf16)t[kq+j][c]; o1[j] = (bf16)t[kq+8+j][c]; }
  *(bf16x8*)(wt + (c0 + c) * 512 + k0 + kq) = o0;
  *(bf16x8*)(wt + (c0 + c) * 512 + k0 + kq + 8) = o1;
}

// ---- 128x128 tile GEMM, K=512, A[M][512] bf16, Bt[Ncols][512] bf16 ----
template<int MODE>
__global__ void k_gemm(const bf16* __restrict__ A, const bf16* __restrict__ Bt,
                       bf16* __restrict__ qo, bf16* __restrict__ ko, bf16* __restrict__ vo,
                       float* __restrict__ outp, const float* __restrict__ bo) {
  __shared__ bf16 lA[128 * 64];
  __shared__ bf16 lB[128 * 64];
  const int tid = threadIdx.x;
  const int wid = tid >> 6, lane = tid & 63;
  const int l15 = lane & 15, lq = lane >> 4;
  const int wr = wid >> 1, wc = wid & 1;
  const long long rowtile = (long long)blockIdx.x * 128;
  const long long coltile = (long long)blockIdx.y * 128;

  const bf16* gA[4]; const bf16* gB[4];
  bf16* lAc[4]; bf16* lBc[4];
#pragma unroll
  for (int i = 0; i < 4; ++i) {
    int ci = wid * 4 + i;
    int row = ci * 8 + (lane >> 3);
    int c8 = (lane & 7) ^ (row & 7);
    gA[i] = A + (rowtile + row) * 512 + c8 * 8;
    gB[i] = Bt + (coltile + row) * 512 + c8 * 8;
    lAc[i] = &lA[ci * 512];
    lBc[i] = &lB[ci * 512];
  }
  unsigned aoff[4][2], boff[4][2];
#pragma unroll
  for (int mi = 0; mi < 4; ++mi) {
#pragma unroll
    for (int ks = 0; ks < 2; ++ks) {
      int R = l15 + 16 * mi + 64 * wr;
      aoff[mi][ks] = R * 128 + ((((ks << 2) | lq) ^ (R & 7)) << 4);
      int Rb = l15 + 16 * mi + 64 * wc;
      boff[mi][ks] = Rb * 128 + ((((ks << 2) | lq) ^ (Rb & 7)) << 4);
    }
  }
  f32x4 acc[4][4] = {};
  for (int kt = 0; kt < 8; ++kt) {
#pragma unroll
    for (int i = 0; i < 4; ++i) gload_lds16(gA[i], lAc[i]);
#pragma unroll
    for (int i = 0; i < 4; ++i) gload_lds16(gB[i], lBc[i]);
#pragma unroll
    for (int i = 0; i < 4; ++i) { gA[i] += 64; gB[i] += 64; }
    __syncthreads();
#pragma unroll
    for (int ks = 0; ks < 2; ++ks) {
      bf16x8 af[4], bfr[4];
#pragma unroll
      for (int mi = 0; mi < 4; ++mi) af[mi] = *(const bf16x8*)((const char*)lA + aoff[mi][ks]);
#pragma unroll
      for (int nf = 0; nf < 4; ++nf) bfr[nf] = *(const bf16x8*)((const char*)lB + boff[nf][ks]);
#pragma unroll
      for (int mi = 0; mi < 4; ++mi)
#pragma unroll
        for (int nf = 0; nf < 4; ++nf)
          acc[mi][nf] = mfma16(af[mi], bfr[nf], acc[mi][nf]);
    }
    __syncthreads();
  }
  if (MODE == 0) {
#pragma unroll
    for (int nf = 0; nf < 4; ++nf) {
      const int col = (int)coltile + 64 * wc + nf * 16 + l15;
      const int mat = col >> 9, c5 = col & 511, hh = c5 >> 6, dh = c5 & 63;
#pragma unroll
      for (int mi = 0; mi < 4; ++mi) {
#pragma unroll
        for (int r = 0; r < 4; ++r) {
          const int R = (int)rowtile + 64 * wr + mi * 16 + lq * 4 + r;
          const int bb = R >> 11, n = R & 2047;
          const bf16 bv = (bf16)acc[mi][nf][r];
          const long long bh = bb * 8 + hh;
          if (mat == 0)      qo[(bh * 2048 + n) * 64 + dh] = bv;
          else if (mat == 1) ko[(bh * 2048 + n) * 64 + dh] = bv;
          else               vo[(bh * 64 + dh) * 2048 + n] = bv;
        }
      }
    }
  } else {
#pragma unroll
    for (int nf = 0; nf < 4; ++nf) {
      const int col = (int)coltile + 64 * wc + nf * 16 + l15;
      const float bias = bo[col];
#pragma unroll
      for (int mi = 0; mi < 4; ++mi)
#pragma unroll
        for (int r = 0; r < 4; ++r) {
          const long long R = rowtile + 64 * wr + mi * 16 + lq * 4 + r;
          outp[R * 512 + col] = acc[mi][nf][r] + bias;
        }
    }
  }
}

// ---- flash attention v2 ----
// block = (b, qtile of 64 rows), 16 waves = 8 heads x 2 row-halves, 1024 thr.
// mask tile (64x64 f32) staged in LDS via global_load_lds, double-buffered,
// prefetched one K-tile ahead. P per-wave 16x64 in swizzled LDS.
__global__ __launch_bounds__(1024, 4) void k_attn(
    const bf16* __restrict__ qb, const bf16* __restrict__ kb, const bf16* __restrict__ vt,
    const float* __restrict__ mask, bf16* __restrict__ ao) {
  __shared__ float mbuf[2][64][64];   // 32 KB mask double buffer
  __shared__ bf16 pbuf[16][16 * 64];  // 32 KB, 2 KB per wave
  const int tid = threadIdx.x;
  const int wid = tid >> 6, lane = tid & 63;
  const int l15 = lane & 15, lq = lane >> 4;
  const int h = wid & 7, sub = wid >> 3;
  const int b = blockIdx.y, qt = blockIdx.x;
  const int qbase = qt * 64;
  const bf16* Q = qb + (long long)(b * H_ + h) * N_ * DH_;
  const bf16* K = kb + (long long)(b * H_ + h) * N_ * DH_;
  const bf16* V = vt + (long long)(b * H_ + h) * DH_ * N_;
  const float* mrow = mask + ((long long)b * N_ + qbase) * N_;
  // cooperative mask staging: this thread covers tile row strow, 16B chunk (lane&15)
  const int strow = (wid << 2) + (lane >> 4);
  const float* msrc = mrow + strow * 2048 + ((lane & 15) << 2);
  float* mdst0 = &mbuf[0][wid << 2][0];
  float* mdst1 = &mbuf[1][wid << 2][0];
  char* pbase = (char*)&pbuf[wid][0];

  bf16x8 qf[2][2];
#pragma unroll
  for (int mi = 0; mi < 2; ++mi)
#pragma unroll
    for (int ks = 0; ks < 2; ++ks)
      qf[mi][ks] = *(const bf16x8*)(Q + (qbase + sub * 32 + 16 * mi + l15) * 64 + ks * 32 + lq * 8);

  f32x4 o[2][4] = {};
  float lsum[2][4] = {};

  gload_lds16(msrc, mdst0);   // stage mask tile 0
  __syncthreads();

  for (int jt = 0; jt < 32; ++jt) {
    const int jb = jt * 64;
    if (jt < 31) gload_lds16(msrc + jb + 64, (jt & 1) ? mdst0 : mdst1);  // prefetch jt+1
    bf16x8 kf[4][2];
#pragma unroll
    for (int nf = 0; nf < 4; ++nf)
#pragma unroll
      for (int ks = 0; ks < 2; ++ks)
        kf[nf][ks] = *(const bf16x8*)(K + (jb + 16 * nf + l15) * 64 + ks * 32 + lq * 8);

#pragma unroll
    for (int mi = 0; mi < 2; ++mi) {
      f32x4 s[4];
#pragma unroll
      for (int nf = 0; nf < 4; ++nf) {
        f32x4 z = {0.f, 0.f, 0.f, 0.f};
        s[nf] = mfma16(qf[mi][0], kf[nf][0], z);
      }
#pragma unroll
      for (int nf = 0; nf < 4; ++nf)
        s[nf] = mfma16(qf[mi][1], kf[nf][1], s[nf]);
      // softmax numerator: p = exp2(dot*SC2*(1+mask)); bounded logits, no running max
#pragma unroll
      for (int nf = 0; nf < 4; ++nf) {
        const int colL = nf * 16 + l15;
#pragma unroll
        for (int r = 0; r < 4; ++r) {
          const int rowm = sub * 32 + 16 * mi + 4 * lq + r;   // row in 64-row mask tile
          const float mk = mbuf[jt & 1][rowm][colL];
          const float dsc = s[nf][r] * SC2;
          const float p = EXP2(fmaf(dsc, mk, dsc));
          lsum[mi][r] += p;
          const int rowP = 4 * lq + r;                        // row in 16-row P tile
          const int swz = (colL >> 3) ^ (rowP & 7) ^ (((rowP >> 3) & 1) << 1);
          *(bf16*)(pbase + rowP * 128 + (swz << 4) + ((colL & 7) << 1)) = (bf16)p;
        }
      }
      // PV for this mi (16 q-rows)
#pragma unroll
      for (int ks2 = 0; ks2 < 2; ++ks2) {
        bf16x8 vf[4];
#pragma unroll
        for (int nf = 0; nf < 4; ++nf)
          vf[nf] = *(const bf16x8*)(V + (16 * nf + l15) * 2048 + jb + ks2 * 32 + lq * 8);
        const int pswz = (((ks2 << 2) | lq) ^ (l15 & 7) ^ (((l15 >> 3) & 1) << 1));
        bf16x8 pa = *(const bf16x8*)(pbase + l15 * 128 + (pswz << 4));
#pragma unroll
        for (int nf = 0; nf < 4; ++nf)
          o[mi][nf] = mfma16(pa, vf[nf], o[mi][nf]);
      }
    }
    if (jt < 31) __syncthreads();
  }

  float rinv[2][4];
#pragma unroll
  for (int mi = 0; mi < 2; ++mi)
#pragma unroll
    for (int r = 0; r < 4; ++r) {
      float v = lsum[mi][r];
      v += __shfl_xor(v, 1); v += __shfl_xor(v, 2);
      v += __shfl_xor(v, 4); v += __shfl_xor(v, 8);
      rinv[mi][r] = 1.0f / v;
    }
#pragma unroll
  for (int mi = 0; mi < 2; ++mi)
#pragma unroll
    for (int nf = 0; nf < 4; ++nf)
#pragma unroll
      for (int r = 0; r < 4; ++r) {
        const long long rowg = (long long)b * N_ + qbase + sub * 32 + 16 * mi + 4 * lq + r;
        const int col = h * 64 + nf * 16 + l15;
        ao[rowg * 512 + col] = (bf16)(o[mi][nf][r] * rinv[mi][r]);
      }
}

extern "C" void kernel_launch(void* const* d_in, const int* in_sizes, int n_in,
                              void* d_out, int out_size, void* d_ws, size_t ws_size,
                              hipStream_t stream) {
  const float* x    = (const float*)d_in[0];
  const float* mask = (const float*)d_in[1];
  const float* Wq   = (const float*)d_in[2];
  const float* Wk   = (const float*)d_in[3];
  const float* Wv   = (const float*)d_in[4];
  const float* Wo   = (const float*)d_in[5];
  const float* bo   = (const float*)d_in[6];
  float* out = (float*)d_out;
  char* ws = (char*)d_ws;

  const size_t SZ_XB = (size_t)16384 * 512 * 2;
  const size_t SZ_W3 = (size_t)1536 * 512 * 2;
  const size_t SZ_WO = (size_t)512 * 512 * 2;
  const size_t SZ_T  = (size_t)64 * 2048 * 64 * 2;

  bf16* xb    = (bf16*)ws;
  bf16* wqkvT = (bf16*)(ws + SZ_XB);
  bf16* woT   = (bf16*)(ws + SZ_XB + SZ_W3);
  bf16* qbuf  = (bf16*)(ws + SZ_XB + SZ_W3 + SZ_WO);
  bf16* kbuf  = (bf16*)((char*)qbuf + SZ_T);
  bf16* vtb   = (bf16*)((char*)kbuf + SZ_T);
  bf16* aob   = xb;  // x dead after QKV GEMM

  k_cvt_x<<<dim3(4096), dim3(256), 0, stream>>>(x, xb);
  k_wt<<<dim3(8, 8), dim3(256), 0, stream>>>(Wq, wqkvT);
  k_wt<<<dim3(8, 8), dim3(256), 0, stream>>>(Wk, wqkvT + 512 * 512);
  k_wt<<<dim3(8, 8), dim3(256), 0, stream>>>(Wv, wqkvT + 2 * 512 * 512);
  k_wt<<<dim3(8, 8), dim3(256), 0, stream>>>(Wo, woT);
  k_gemm<0><<<dim3(128, 12), dim3(256), 0, stream>>>(xb, wqkvT, qbuf, kbuf, vtb, nullptr, nullptr);
  k_attn<<<dim3(32, 8), dim3(1024), 0, stream>>>(qbuf, kbuf, vtb, mask, aob);
  k_gemm<1><<<dim3(128, 4), dim3(256), 0, stream>>>(aob, woT, nullptr, nullptr, nullptr, out, bo);
}

// Round 3
// 227.298 us; speedup vs baseline: 3.5618x; 2.7855x over previous
//
#include <hip/hip_runtime.h>

typedef __bf16 bf16;
typedef __bf16 bf16x8 __attribute__((ext_vector_type(8)));
typedef float  f32x4  __attribute__((ext_vector_type(4)));

#define B_  8
#define N_  2048
#define D_  512
#define H_  8
#define DH_ 64
static constexpr float SC2 = 0.18033688011112042f; // (1/8) * log2(e)

#if defined(__has_builtin)
#if __has_builtin(__builtin_amdgcn_exp2f)
#define EXP2(x) __builtin_amdgcn_exp2f(x)
#else
#define EXP2(x) exp2f(x)
#endif
#else
#define EXP2(x) exp2f(x)
#endif

__device__ __forceinline__ f32x4 mfma16(bf16x8 a, bf16x8 b, f32x4 c) {
  return __builtin_amdgcn_mfma_f32_16x16x32_bf16(a, b, c, 0, 0, 0);
}

__device__ __forceinline__ void gload_lds16(const void* g, void* l) {
  __builtin_amdgcn_global_load_lds((__attribute__((address_space(1))) void*)g,
                                   (__attribute__((address_space(3))) void*)l, 16, 0, 0);
}

// ---- convert x (f32) -> bf16, 8 elems/thread ----
__global__ void k_cvt_x(const float* __restrict__ x, bf16* __restrict__ xb) {
  int i = blockIdx.x * blockDim.x + threadIdx.x;
  const float4* p = (const float4*)x;
  float4 a = p[2*i], b = p[2*i+1];
  bf16x8 o;
  o[0]=(bf16)a.x; o[1]=(bf16)a.y; o[2]=(bf16)a.z; o[3]=(bf16)a.w;
  o[4]=(bf16)b.x; o[5]=(bf16)b.y; o[6]=(bf16)b.z; o[7]=(bf16)b.w;
  ((bf16x8*)xb)[i] = o;
}

// ---- transpose-convert one 512x512 f32 weight -> bf16 W^T ----
__global__ void k_wt(const float* __restrict__ w, bf16* __restrict__ wt) {
  __shared__ float t[64][65];
  const int c0 = blockIdx.x * 64, k0 = blockIdx.y * 64;
  const int r = threadIdx.x >> 2, q4 = (threadIdx.x & 3) * 16;
#pragma unroll
  for (int j = 0; j < 16; j += 4) {
    float4 v = *(const float4*)(w + (k0 + r) * 512 + c0 + q4 + j);
    t[r][q4+j] = v.x; t[r][q4+j+1] = v.y; t[r][q4+j+2] = v.z; t[r][q4+j+3] = v.w;
  }
  __syncthreads();
  const int c = threadIdx.x >> 2, kq = (threadIdx.x & 3) * 16;
  bf16x8 o0, o1;
#pragma unroll
  for (int j = 0; j < 8; ++j) { o0[j] = (bf16)t[kq+j][c]; o1[j] = (bf16)t[kq+8+j][c]; }
  *(bf16x8*)(wt + (c0 + c) * 512 + k0 + kq) = o0;
  *(bf16x8*)(wt + (c0 + c) * 512 + k0 + kq + 8) = o1;
}

// ---- 128x128 tile GEMM, K=512 ----
template<int MODE>
__global__ void k_gemm(const bf16* __restrict__ A, const bf16* __restrict__ Bt,
                       bf16* __restrict__ qo, bf16* __restrict__ ko, bf16* __restrict__ vo,
                       float* __restrict__ outp, const float* __restrict__ bo) {
  __shared__ bf16 lA[128 * 64];
  __shared__ bf16 lB[128 * 64];
  const int tid = threadIdx.x;
  const int wid = tid >> 6, lane = tid & 63;
  const int l15 = lane & 15, lq = lane >> 4;
  const int wr = wid >> 1, wc = wid & 1;
  const long long rowtile = (long long)blockIdx.x * 128;
  const long long coltile = (long long)blockIdx.y * 128;

  const bf16* gA[4]; const bf16* gB[4];
  bf16* lAc[4]; bf16* lBc[4];
#pragma unroll
  for (int i = 0; i < 4; ++i) {
    int ci = wid * 4 + i;
    int row = ci * 8 + (lane >> 3);
    int c8 = (lane & 7) ^ (row & 7);
    gA[i] = A + (rowtile + row) * 512 + c8 * 8;
    gB[i] = Bt + (coltile + row) * 512 + c8 * 8;
    lAc[i] = &lA[ci * 512];
    lBc[i] = &lB[ci * 512];
  }
  unsigned aoff[4][2], boff[4][2];
#pragma unroll
  for (int mi = 0; mi < 4; ++mi) {
#pragma unroll
    for (int ks = 0; ks < 2; ++ks) {
      int R = l15 + 16 * mi + 64 * wr;
      aoff[mi][ks] = R * 128 + ((((ks << 2) | lq) ^ (R & 7)) << 4);
      int Rb = l15 + 16 * mi + 64 * wc;
      boff[mi][ks] = Rb * 128 + ((((ks << 2) | lq) ^ (Rb & 7)) << 4);
    }
  }
  f32x4 acc[4][4] = {};
  for (int kt = 0; kt < 8; ++kt) {
#pragma unroll
    for (int i = 0; i < 4; ++i) gload_lds16(gA[i], lAc[i]);
#pragma unroll
    for (int i = 0; i < 4; ++i) gload_lds16(gB[i], lBc[i]);
#pragma unroll
    for (int i = 0; i < 4; ++i) { gA[i] += 64; gB[i] += 64; }
    __syncthreads();
#pragma unroll
    for (int ks = 0; ks < 2; ++ks) {
      bf16x8 af[4], bfr[4];
#pragma unroll
      for (int mi = 0; mi < 4; ++mi) af[mi] = *(const bf16x8*)((const char*)lA + aoff[mi][ks]);
#pragma unroll
      for (int nf = 0; nf < 4; ++nf) bfr[nf] = *(const bf16x8*)((const char*)lB + boff[nf][ks]);
#pragma unroll
      for (int mi = 0; mi < 4; ++mi)
#pragma unroll
        for (int nf = 0; nf < 4; ++nf)
          acc[mi][nf] = mfma16(af[mi], bfr[nf], acc[mi][nf]);
    }
    __syncthreads();
  }
  if (MODE == 0) {
#pragma unroll
    for (int nf = 0; nf < 4; ++nf) {
      const int col = (int)coltile + 64 * wc + nf * 16 + l15;
      const int mat = col >> 9, c5 = col & 511, hh = c5 >> 6, dh = c5 & 63;
#pragma unroll
      for (int mi = 0; mi < 4; ++mi) {
#pragma unroll
        for (int r = 0; r < 4; ++r) {
          const int R = (int)rowtile + 64 * wr + mi * 16 + lq * 4 + r;
          const int bb = R >> 11, n = R & 2047;
          const bf16 bv = (bf16)acc[mi][nf][r];
          const long long bh = bb * 8 + hh;
          if (mat == 0)      qo[(bh * 2048 + n) * 64 + dh] = bv;
          else if (mat == 1) ko[(bh * 2048 + n) * 64 + dh] = bv;
          else               vo[(bh * 64 + dh) * 2048 + n] = bv;
        }
      }
    }
  } else {
#pragma unroll
    for (int nf = 0; nf < 4; ++nf) {
      const int col = (int)coltile + 64 * wc + nf * 16 + l15;
      const float bias = bo[col];
#pragma unroll
      for (int mi = 0; mi < 4; ++mi)
#pragma unroll
        for (int r = 0; r < 4; ++r) {
          const long long R = rowtile + 64 * wr + mi * 16 + lq * 4 + r;
          outp[R * 512 + col] = acc[mi][nf][r] + bias;
        }
    }
  }
}

// ---- flash attention v3 ----
// block = (b, h, qtile of 128 rows); 512 thr = 8 waves x 16 q-rows.
// K/V 64x64 tiles in LDS (global_load_lds, pre-swizzled src, double-buffered).
// mask: global -> register double-buffer (one consumer lane per element).
// Inverse-XCD swizzle: 8 head-blocks sharing a (b,qt) mask tile -> same XCD.
__global__ __launch_bounds__(512, 4) void k_attn(
    const bf16* __restrict__ qb, const bf16* __restrict__ kb, const bf16* __restrict__ vt,
    const float* __restrict__ mask, bf16* __restrict__ ao) {
  __shared__ bf16 kvb[2][2][64 * 64];   // [buf][K=0/V=1], 32 KB
  __shared__ bf16 pb[8][16 * 64];       // per-wave P, 16 KB
  const int tid = threadIdx.x;
  const int wid = tid >> 6, lane = tid & 63;
  const int l15 = lane & 15, lq = lane >> 4;
  const int p = blockIdx.x;
  const int xcd = p & 7, kk = p >> 3;
  const int g = xcd * 16 + (kk >> 3), h = kk & 7;
  const int b = g >> 4, qt = g & 15;
  const long long bh = b * 8 + h;
  const bf16* Q = qb + bh * (2048ll * 64);
  const bf16* K = kb + bh * (2048ll * 64);
  const bf16* V = vt + bh * (64ll * 2048);
  const int qrow0 = qt * 128 + wid * 16;
  const float* mbase = mask + ((long long)b * 2048 + qrow0 + lq * 4) * 2048 + l15;

  // staging: thread t covers LDS bytes [t*16, t*16+16); inverse-swizzled global src
  const int srow = tid >> 3;
  const int sc = (tid & 7) ^ (srow & 7);
  const bf16* kg = K + srow * 64 + sc * 8;     // K rows = n
  const bf16* vg = V + srow * 2048 + sc * 8;   // V^T rows = dh
  bf16* kl0 = &kvb[0][0][tid * 8]; bf16* vl0 = &kvb[0][1][tid * 8];
  bf16* kl1 = &kvb[1][0][tid * 8]; bf16* vl1 = &kvb[1][1][tid * 8];
  char* pw = (char*)&pb[wid][0];

  bf16x8 qf[2];
#pragma unroll
  for (int ks = 0; ks < 2; ++ks)
    qf[ks] = *(const bf16x8*)(Q + (qrow0 + l15) * 64 + ks * 32 + lq * 8);

  f32x4 o[4] = {};
  float lsum[4] = {};
  float mA[16], mB[16];

  auto mload = [&](float (&m)[16], int jb) {
#pragma unroll
    for (int nf = 0; nf < 4; ++nf)
#pragma unroll
      for (int r = 0; r < 4; ++r)
        m[nf * 4 + r] = mbase[r * 2048 + jb + nf * 16];
  };

  auto compute = [&](int bi, const float (&m)[16]) {
    const bf16* kbL = &kvb[bi][0][0];
    const bf16* vbL = &kvb[bi][1][0];
    f32x4 s[4];
#pragma unroll
    for (int nf = 0; nf < 4; ++nf) {
      const int row = nf * 16 + l15;
      const bf16x8 kf = *(const bf16x8*)(kbL + row * 64 + ((lq ^ (row & 7)) << 3));
      f32x4 z = {0.f, 0.f, 0.f, 0.f};
      s[nf] = mfma16(qf[0], kf, z);
    }
#pragma unroll
    for (int nf = 0; nf < 4; ++nf) {
      const int row = nf * 16 + l15;
      const bf16x8 kf = *(const bf16x8*)(kbL + row * 64 + (((4 + lq) ^ (row & 7)) << 3));
      s[nf] = mfma16(qf[1], kf, s[nf]);
    }
#pragma unroll
    for (int nf = 0; nf < 4; ++nf) {
#pragma unroll
      for (int r = 0; r < 4; ++r) {
        const float dsc = s[nf][r] * SC2;
        const float pe = EXP2(fmaf(dsc, m[nf * 4 + r], dsc));
        lsum[r] += pe;
        const int colL = nf * 16 + l15;
        const int slot = ((colL >> 3) ^ (lq << 1) ^ r) & 7;
        *(bf16*)(pw + (lq * 4 + r) * 128 + slot * 16 + ((colL & 7) << 1)) = (bf16)pe;
      }
    }
#pragma unroll
    for (int ks = 0; ks < 2; ++ks) {
      const int c = ks * 4 + lq;
      const int slotp = (c ^ ((l15 >> 2) << 1) ^ (l15 & 3)) & 7;
      const bf16x8 pa = *(const bf16x8*)(pw + l15 * 128 + slotp * 16);
#pragma unroll
      for (int nf = 0; nf < 4; ++nf) {
        const int row = nf * 16 + l15;
        const bf16x8 vf = *(const bf16x8*)(vbL + row * 64 + ((c ^ (row & 7)) << 3));
        o[nf] = mfma16(pa, vf, o[nf]);
      }
    }
  };

  // prologue: stage tile 0, mask tile 0
  gload_lds16(kg, kl0); gload_lds16(vg, vl0);
  mload(mA, 0);
  __syncthreads();

  for (int jt = 0; jt < 32; jt += 2) {
    // stage jt+1 into buf1 (buf1 reads ended at previous barrier)
    gload_lds16(kg + (jt + 1) * 4096, kl1);
    gload_lds16(vg + (jt + 1) * 64, vl1);
    mload(mB, (jt + 1) * 64);
    compute(0, mA);
    __syncthreads();
    if (jt + 2 < 32) {
      gload_lds16(kg + (jt + 2) * 4096, kl0);
      gload_lds16(vg + (jt + 2) * 64, vl0);
      mload(mA, (jt + 2) * 64);
    }
    compute(1, mB);
    __syncthreads();
  }

  float rinv[4];
#pragma unroll
  for (int r = 0; r < 4; ++r) {
    float v2 = lsum[r];
    v2 += __shfl_xor(v2, 1); v2 += __shfl_xor(v2, 2);
    v2 += __shfl_xor(v2, 4); v2 += __shfl_xor(v2, 8);
    rinv[r] = 1.0f / v2;
  }
#pragma unroll
  for (int nf = 0; nf < 4; ++nf)
#pragma unroll
    for (int r = 0; r < 4; ++r) {
      const long long rowg = (long long)b * 2048 + qrow0 + lq * 4 + r;
      ao[rowg * 512 + h * 64 + nf * 16 + l15] = (bf16)(o[nf][r] * rinv[r]);
    }
}

extern "C" void kernel_launch(void* const* d_in, const int* in_sizes, int n_in,
                              void* d_out, int out_size, void* d_ws, size_t ws_size,
                              hipStream_t stream) {
  const float* x    = (const float*)d_in[0];
  const float* mask = (const float*)d_in[1];
  const float* Wq   = (const float*)d_in[2];
  const float* Wk   = (const float*)d_in[3];
  const float* Wv   = (const float*)d_in[4];
  const float* Wo   = (const float*)d_in[5];
  const float* bo   = (const float*)d_in[6];
  float* out = (float*)d_out;
  char* ws = (char*)d_ws;

  const size_t SZ_XB = (size_t)16384 * 512 * 2;
  const size_t SZ_W3 = (size_t)1536 * 512 * 2;
  const size_t SZ_WO = (size_t)512 * 512 * 2;
  const size_t SZ_T  = (size_t)64 * 2048 * 64 * 2;

  bf16* xb    = (bf16*)ws;
  bf16* wqkvT = (bf16*)(ws + SZ_XB);
  bf16* woT   = (bf16*)(ws + SZ_XB + SZ_W3);
  bf16* qbuf  = (bf16*)(ws + SZ_XB + SZ_W3 + SZ_WO);
  bf16* kbuf  = (bf16*)((char*)qbuf + SZ_T);
  bf16* vtb   = (bf16*)((char*)kbuf + SZ_T);
  bf16* aob   = xb;  // x dead after QKV GEMM

  k_cvt_x<<<dim3(4096), dim3(256), 0, stream>>>(x, xb);
  k_wt<<<dim3(8, 8), dim3(256), 0, stream>>>(Wq, wqkvT);
  k_wt<<<dim3(8, 8), dim3(256), 0, stream>>>(Wk, wqkvT + 512 * 512);
  k_wt<<<dim3(8, 8), dim3(256), 0, stream>>>(Wv, wqkvT + 2 * 512 * 512);
  k_wt<<<dim3(8, 8), dim3(256), 0, stream>>>(Wo, woT);
  k_gemm<0><<<dim3(128, 12), dim3(256), 0, stream>>>(xb, wqkvT, qbuf, kbuf, vtb, nullptr, nullptr);
  k_attn<<<dim3(1024), dim3(512), 0, stream>>>(qbuf, kbuf, vtb, mask, aob);
  k_gemm<1><<<dim3(128, 4), dim3(256), 0, stream>>>(aob, woT, nullptr, nullptr, nullptr, out, bo);
}